// Round 1
// baseline (237.780 us; speedup 1.0000x reference)
//
#include <hip/hip_runtime.h>

typedef __bf16 bf16x8 __attribute__((ext_vector_type(8)));
typedef float f32x4 __attribute__((ext_vector_type(4)));

#define MFMA16(a, b, c) __builtin_amdgcn_mfma_f32_16x16x32_bf16((a), (b), (c), 0, 0, 0)

// ws element offsets (__bf16 units)
#define WT_OFF   0        // Wt  [96][1024]   (W^T for Q|K|V, Wq pre-scaled)
#define WOT_OFF  98304    // Wot [1024][32]   (Wo^T)
#define QB_OFF   131072   // Qb  [16384][32]
#define KB_OFF   655360   // Kb  [16384][32]
#define VT_OFF   1179648  // Vt  [4][32][4096]

#define SCALE_R 0.17677669529663689f  // 1/sqrt(32)

__global__ __launch_bounds__(256) void prep_kernel(
    const float* __restrict__ Wq, const float* __restrict__ Wk,
    const float* __restrict__ Wv, const float* __restrict__ Wo,
    __bf16* __restrict__ ws) {
  int idx = blockIdx.x * 256 + threadIdx.x;
  if (idx < 98304) {            // Wt[n][d] = W[d][n], n in [0,96)
    int n = idx >> 10, d = idx & 1023;
    float v;
    if (n < 32)      v = Wq[d * 32 + n] * SCALE_R;
    else if (n < 64) v = Wk[d * 32 + (n - 32)];
    else             v = Wv[d * 32 + (n - 64)];
    ws[WT_OFF + idx] = (__bf16)v;
  } else if (idx < 131072) {    // Wot[d][r] = Wo[r][d]
    int j = idx - 98304;
    int d = j >> 5, r = j & 31;
    ws[WOT_OFF + j] = (__bf16)Wo[r * 1024 + d];
  }
}

// QKV projection: [16384 x 1024] @ [1024 x 96] in bf16 MFMA, fp32 accum.
__global__ __launch_bounds__(256) void proj_kernel(
    const float* __restrict__ x, const float* __restrict__ bq,
    const float* __restrict__ bk, const float* __restrict__ bv,
    __bf16* __restrict__ ws) {
  const __bf16* Wt = ws + WT_OFF;
  __bf16* Qb = ws + QB_OFF;
  __bf16* Kb = ws + KB_OFF;
  __bf16* Vt = ws + VT_OFF;
  int tid = threadIdx.x;
  int lane = tid & 63, w = tid >> 6;
  int c = lane & 15, g = lane >> 4;
  int rowA = blockIdx.x * 64 + w * 16 + c;     // A-frag row (lane&15)
  const float* xrow = x + (size_t)rowA * 1024 + g * 8;
  f32x4 acc[6];
#pragma unroll
  for (int i = 0; i < 6; i++) acc[i] = (f32x4){0.f, 0.f, 0.f, 0.f};
#pragma unroll 4
  for (int ks = 0; ks < 32; ks++) {
    float4 xa = *(const float4*)(xrow + ks * 32);
    float4 xb = *(const float4*)(xrow + ks * 32 + 4);
    bf16x8 a;
    a[0] = (__bf16)xa.x; a[1] = (__bf16)xa.y; a[2] = (__bf16)xa.z; a[3] = (__bf16)xa.w;
    a[4] = (__bf16)xb.x; a[5] = (__bf16)xb.y; a[6] = (__bf16)xb.z; a[7] = (__bf16)xb.w;
#pragma unroll
    for (int nf = 0; nf < 6; nf++) {
      bf16x8 b = *(const bf16x8*)(Wt + (nf * 16 + c) * 1024 + ks * 32 + g * 8);
      acc[nf] = MFMA16(a, b, acc[nf]);
    }
  }
  // D-frag: col = nf*16 + (lane&15), row = row0 + reg
  int row0 = blockIdx.x * 64 + w * 16 + g * 4;
#pragma unroll
  for (int nf = 0; nf < 6; nf++) {
    int n = nf * 16 + c;
    float bias = (n < 32) ? bq[n] * SCALE_R : (n < 64 ? bk[n - 32] : bv[n - 64]);
#pragma unroll
    for (int r = 0; r < 4; r++) {
      int row = row0 + r;
      float v = acc[nf][r] + bias;
      if (n < 32)      Qb[row * 32 + n] = (__bf16)v;
      else if (n < 64) Kb[row * 32 + (n - 32)] = (__bf16)v;
      else {
        int batch = row >> 12, s = row & 4095;
        Vt[(batch * 32 + (n - 64)) * 4096 + s] = (__bf16)v;
      }
    }
  }
}

// Flash attention + fused output projection. One wave per block, 16 Q rows.
__global__ __launch_bounds__(64) void flash_kernel(
    const float* __restrict__ bo, float* __restrict__ out,
    const __bf16* __restrict__ ws) {
  const __bf16* Wot = ws + WOT_OFF;
  const __bf16* Qb  = ws + QB_OFF;
  const __bf16* Kb  = ws + KB_OFF;
  const __bf16* Vt  = ws + VT_OFF;
  __shared__ __bf16 pbuf[16 * 72];  // [16 rows][64 keys], 144B row stride (padded)
  __shared__ __bf16 abuf[16 * 40];  // [16 rows][32 r],   80B row stride (padded)
  int lane = threadIdx.x;
  int c = lane & 15, g = lane >> 4;
  int batch = blockIdx.x >> 8, qt = blockIdx.x & 255;
  int qrow0 = batch * 4096 + qt * 16;
  const __bf16* Kbb = Kb + (size_t)batch * 4096 * 32;
  const __bf16* Vtb = Vt + (size_t)batch * 32 * 4096;

  const f32x4 zero = {0.f, 0.f, 0.f, 0.f};
  // Q A-frag: row = lane&15, k = 8*(lane>>4)+j  (scale already folded into Wq)
  bf16x8 aq = *(const bf16x8*)(Qb + (qrow0 + c) * 32 + g * 8);
  f32x4 acc0 = zero, acc1 = zero;
  float m[4], lsum[4];
#pragma unroll
  for (int r = 0; r < 4; r++) { m[r] = -1e30f; lsum[r] = 0.0f; }

  // prefetch KV tile 0: bk[i] = keys i*16..+15; bv[rf*2+ks] = V^T frag
  bf16x8 bk[4], bv[4];
#pragma unroll
  for (int i = 0; i < 4; i++)
    bk[i] = *(const bf16x8*)(Kbb + (i * 16 + c) * 32 + g * 8);
#pragma unroll
  for (int i = 0; i < 4; i++)
    bv[i] = *(const bf16x8*)(Vtb + ((i >> 1) * 16 + c) * 4096 + (i & 1) * 32 + g * 8);

#pragma unroll 2
  for (int kt = 0; kt < 64; kt++) {
    int ktn = (kt + 1 < 64) ? kt + 1 : 63;
    bf16x8 nk[4], nv[4];
#pragma unroll
    for (int i = 0; i < 4; i++)
      nk[i] = *(const bf16x8*)(Kbb + (ktn * 64 + i * 16 + c) * 32 + g * 8);
#pragma unroll
    for (int i = 0; i < 4; i++)
      nv[i] = *(const bf16x8*)(Vtb + ((i >> 1) * 16 + c) * 4096 + ktn * 64 + (i & 1) * 32 + g * 8);

    // scores: D[row=4g+reg][key=16i+c]
    f32x4 s[4];
#pragma unroll
    for (int i = 0; i < 4; i++) s[i] = MFMA16(aq, bk[i], zero);

    // online softmax per query row (row-reduce = 16-lane shfl group)
    float p[4][4];
#pragma unroll
    for (int r = 0; r < 4; r++) {
      float tmax = fmaxf(fmaxf(s[0][r], s[1][r]), fmaxf(s[2][r], s[3][r]));
#pragma unroll
      for (int msk = 1; msk < 16; msk <<= 1)
        tmax = fmaxf(tmax, __shfl_xor(tmax, msk, 64));
      float mn = fmaxf(m[r], tmax);
      float corr = __expf(m[r] - mn);
      m[r] = mn;
      float ps = 0.0f;
#pragma unroll
      for (int i = 0; i < 4; i++) { p[i][r] = __expf(s[i][r] - mn); ps += p[i][r]; }
#pragma unroll
      for (int msk = 1; msk < 16; msk <<= 1) ps += __shfl_xor(ps, msk, 64);
      lsum[r] = lsum[r] * corr + ps;
      acc0[r] *= corr;
      acc1[r] *= corr;
    }

    // transpose P through LDS: write (row=4g+reg, key=16i+c), read as A-frags
    __syncthreads();
#pragma unroll
    for (int i = 0; i < 4; i++)
#pragma unroll
      for (int r = 0; r < 4; r++)
        pbuf[(4 * g + r) * 72 + i * 16 + c] = (__bf16)p[i][r];
    __syncthreads();
    bf16x8 ap0 = *(const bf16x8*)(pbuf + c * 72 + g * 8);        // keys 0..31
    bf16x8 ap1 = *(const bf16x8*)(pbuf + c * 72 + 32 + g * 8);   // keys 32..63

    acc0 = MFMA16(ap0, bv[0], acc0);
    acc0 = MFMA16(ap1, bv[1], acc0);
    acc1 = MFMA16(ap0, bv[2], acc1);
    acc1 = MFMA16(ap1, bv[3], acc1);

#pragma unroll
    for (int i = 0; i < 4; i++) { bk[i] = nk[i]; bv[i] = nv[i]; }
  }

  // normalize, bounce attn through LDS, fused @ Wo + bo
#pragma unroll
  for (int r = 0; r < 4; r++) {
    float inv = 1.0f / lsum[r];
    acc0[r] *= inv;
    acc1[r] *= inv;
  }
  __syncthreads();
#pragma unroll
  for (int r = 0; r < 4; r++) {
    abuf[(4 * g + r) * 40 + c] = (__bf16)acc0[r];
    abuf[(4 * g + r) * 40 + 16 + c] = (__bf16)acc1[r];
  }
  __syncthreads();
  bf16x8 aa = *(const bf16x8*)(abuf + c * 40 + g * 8);
#pragma unroll 8
  for (int nf = 0; nf < 64; nf++) {
    bf16x8 bw = *(const bf16x8*)(Wot + (nf * 16 + c) * 32 + g * 8);
    f32x4 o = MFMA16(aa, bw, zero);
    float bias = bo[nf * 16 + c];
    float* op = out + (size_t)(qrow0 + 4 * g) * 1024 + nf * 16 + c;
#pragma unroll
    for (int r = 0; r < 4; r++)
      op[(size_t)r * 1024] = o[r] + bias;
  }
}

extern "C" void kernel_launch(void* const* d_in, const int* in_sizes, int n_in,
                              void* d_out, int out_size, void* d_ws, size_t ws_size,
                              hipStream_t stream) {
  const float* x  = (const float*)d_in[0];
  const float* Wq = (const float*)d_in[1];
  const float* bq = (const float*)d_in[2];
  const float* Wk = (const float*)d_in[3];
  const float* bk = (const float*)d_in[4];
  const float* Wv = (const float*)d_in[5];
  const float* bv = (const float*)d_in[6];
  const float* Wo = (const float*)d_in[7];
  const float* bo = (const float*)d_in[8];
  float* out = (float*)d_out;
  __bf16* ws = (__bf16*)d_ws;
  prep_kernel<<<dim3(512), dim3(256), 0, stream>>>(Wq, Wk, Wv, Wo, ws);
  proj_kernel<<<dim3(256), dim3(256), 0, stream>>>(x, bq, bk, bv, ws);
  flash_kernel<<<dim3(1024), dim3(64), 0, stream>>>(bo, out, ws);
}

// Round 6
// 218.358 us; speedup vs baseline: 1.0889x; 1.0889x over previous
//
#include <hip/hip_runtime.h>

typedef __bf16 bf16x8 __attribute__((ext_vector_type(8)));
typedef float f32x4 __attribute__((ext_vector_type(4)));

#define MFMA16(a, b, c) __builtin_amdgcn_mfma_f32_16x16x32_bf16((a), (b), (c), 0, 0, 0)

// ws element offsets (__bf16 units)
#define WT_OFF   0        // Wt  [96][1024]   (W^T for Q|K|V, Wq pre-scaled by scale*log2e)
#define WOT_OFF  98304    // Wot [1024][32]   (Wo^T)
#define QB_OFF   131072   // Qb  [16384][32]
#define KB_OFF   655360   // Kb  [16384][32]
#define VT_OFF   1179648  // Vt  [4][32][4096]

#define SCALE_QL (0.17677669529663689f * 1.4426950408889634f)  // rank^-0.5 * log2(e)

__device__ __forceinline__ void load_lds16(void* lds, const void* gsrc) {
  __builtin_amdgcn_global_load_lds(
      (const __attribute__((address_space(1))) unsigned int*)gsrc,
      (__attribute__((address_space(3))) unsigned int*)lds, 16, 0, 0);
}

__global__ __launch_bounds__(256) void prep_kernel(
    const float* __restrict__ Wq, const float* __restrict__ Wk,
    const float* __restrict__ Wv, const float* __restrict__ Wo,
    __bf16* __restrict__ ws) {
  int idx = blockIdx.x * 256 + threadIdx.x;
  if (idx < 98304) {            // Wt[n][d] = W[d][n], n in [0,96)
    int n = idx >> 10, d = idx & 1023;
    float v;
    if (n < 32)      v = Wq[d * 32 + n] * SCALE_QL;
    else if (n < 64) v = Wk[d * 32 + (n - 32)];
    else             v = Wv[d * 32 + (n - 64)];
    ws[WT_OFF + idx] = (__bf16)v;
  } else if (idx < 131072) {    // Wot[d][r] = Wo[r][d]
    int j = idx - 98304;
    int d = j >> 5, r = j & 31;
    ws[WOT_OFF + j] = (__bf16)Wo[r * 1024 + d];
  }
}

// ---------------- QKV projection -----------------------------------------
// 1024 blocks x 64 threads (1 wave, 16 rows). x staged fp32 via
// global_load_lds 4-deep (counted vmcnt, no barriers), W frags reg-prefetched.
__device__ __forceinline__ void stage_x(float* lbase, const float* x, int r0,
                                        int tt, int lane) {
#pragma unroll
  for (int j = 0; j < 4; ++j) {
    int row = j * 4 + (lane >> 4);
    int ch = lane & 15;
    int gc = (ch & 8) | ((ch & 7) ^ (row & 7));   // XOR-swizzle 16B chunks
    const float* src = x + (size_t)(r0 + row) * 1024 + tt * 64 + gc * 4;
    load_lds16(lbase + j * 256, src);
  }
}

__device__ __forceinline__ void load_w(bf16x8* w, const __bf16* Wt, int t,
                                       int c, int g) {
#pragma unroll
  for (int ks = 0; ks < 2; ++ks)
#pragma unroll
    for (int nf = 0; nf < 6; ++nf)
      w[ks * 6 + nf] =
          *(const bf16x8*)(Wt + (size_t)(nf * 16 + c) * 1024 + t * 64 + ks * 32 + g * 8);
}

__global__ __launch_bounds__(64) void proj_kernel(
    const float* __restrict__ x, const float* __restrict__ bq,
    const float* __restrict__ bk, const float* __restrict__ bv,
    __bf16* __restrict__ ws) {
  __shared__ float xlds[4 * 16 * 64];  // 4 bufs x (16 rows x 64 f32), swizzled
  const __bf16* Wt = ws + WT_OFF;
  __bf16* Qb = ws + QB_OFF;
  __bf16* Kb = ws + KB_OFF;
  __bf16* Vt = ws + VT_OFF;
  int lane = threadIdx.x;
  int c = lane & 15, g = lane >> 4;
  int r0 = blockIdx.x * 16;

  // prologue: stage tiles 0..3, then W(0)  (issue order matters for vmcnt)
#pragma unroll
  for (int tt = 0; tt < 4; ++tt) stage_x(xlds + tt * 1024, x, r0, tt, lane);
  __builtin_amdgcn_sched_barrier(0);
  bf16x8 wcur[12], wnext[12];
  load_w(wcur, Wt, 0, c, g);
  __builtin_amdgcn_sched_barrier(0);

  f32x4 acc[6];
#pragma unroll
  for (int i = 0; i < 6; ++i) acc[i] = (f32x4){0.f, 0.f, 0.f, 0.f};

  for (int t = 0; t < 16; ++t) {
    __builtin_amdgcn_sched_barrier(0);
    if (t + 1 < 16) load_w(wnext, Wt, t + 1, c, g);   // W(t+1): 12 loads
    __builtin_amdgcn_sched_barrier(0);
    // wait: x(t) and W(t) complete. Queue newest-first: W(t+1):12, x(t+3):4.
    if (t == 0)      asm volatile("s_waitcnt vmcnt(12)" ::: "memory");
    else if (t < 12) asm volatile("s_waitcnt vmcnt(16)" ::: "memory");
    else             asm volatile("s_waitcnt vmcnt(0)" ::: "memory");
    __builtin_amdgcn_sched_barrier(0);

    const float* xt = xlds + (t & 3) * 1024;
#pragma unroll
    for (int ks = 0; ks < 2; ++ks) {
      int cha = (ks << 3) | ((2 * g) ^ (c & 7));
      int chb = (ks << 3) | (((2 * g) | 1) ^ (c & 7));
      f32x4 xa = *(const f32x4*)(xt + c * 64 + cha * 4);
      f32x4 xb = *(const f32x4*)(xt + c * 64 + chb * 4);
      bf16x8 a;
      a[0] = (__bf16)xa[0]; a[1] = (__bf16)xa[1];
      a[2] = (__bf16)xa[2]; a[3] = (__bf16)xa[3];
      a[4] = (__bf16)xb[0]; a[5] = (__bf16)xb[1];
      a[6] = (__bf16)xb[2]; a[7] = (__bf16)xb[3];
#pragma unroll
      for (int nf = 0; nf < 6; ++nf)
        acc[nf] = MFMA16(a, wcur[ks * 6 + nf], acc[nf]);
    }
    __builtin_amdgcn_sched_barrier(0);
    if (t + 4 < 16) stage_x(xlds + (t & 3) * 1024, x, r0, t + 4, lane);
#pragma unroll
    for (int i = 0; i < 12; ++i) wcur[i] = wnext[i];
  }

  // epilogue: bias + scatter to Qb/Kb/Vt
#pragma unroll
  for (int nf = 0; nf < 6; ++nf) {
    int n = nf * 16 + c;
    float bias = (n < 32) ? bq[n] * SCALE_QL : (n < 64 ? bk[n - 32] : bv[n - 64]);
#pragma unroll
    for (int r = 0; r < 4; ++r) {
      int row = r0 + 4 * g + r;
      float v = acc[nf][r] + bias;
      if (n < 32)      Qb[row * 32 + n] = (__bf16)v;
      else if (n < 64) Kb[row * 32 + (n - 32)] = (__bf16)v;
      else {
        int batch = row >> 12, s = row & 4095;
        Vt[((size_t)(batch * 32 + (n - 64))) * 4096 + s] = (__bf16)v;
      }
    }
  }
}

// ---------------- flash attention + fused out-proj ------------------------
// 256 blocks x 4 waves; block = 64 q rows (16/wave); KV tile 64 staged in LDS
// (double-buffered, shared by all 4 waves). Swapped QK^T: mfma(K,Q) -> S^T,
// softmax nearly lane-local (2+2 shuffles/tile).
__device__ __forceinline__ void stage_kv(__bf16* buf, const __bf16* Kbb,
                                         const __bf16* Vtb, int kt, int w,
                                         int lane) {
  if (w < 2) {  // K tile [64 keys][32 dims], linear
#pragma unroll
    for (int i = 0; i < 2; ++i) {
      int row = w * 32 + i * 16 + (lane >> 2);
      int ch = lane & 3;
      const __bf16* src = Kbb + (size_t)(kt * 64 + row) * 32 + ch * 8;
      load_lds16(buf + w * 1024 + i * 512, src);
    }
  } else {      // V tile [32 rv][64 keys], XOR-swizzled 16B chunks
    int t2 = w - 2;
#pragma unroll
    for (int i = 0; i < 2; ++i) {
      int row = t2 * 16 + i * 8 + (lane >> 3);
      int ch = lane & 7;
      int gc = ch ^ (row & 7);
      const __bf16* src = Vtb + (size_t)row * 4096 + kt * 64 + gc * 8;
      load_lds16(buf + 2048 + t2 * 1024 + i * 512, src);
    }
  }
}

__global__ __launch_bounds__(256) void flash_kernel(
    const float* __restrict__ bo, float* __restrict__ out,
    const __bf16* __restrict__ ws) {
  const __bf16* Wot = ws + WOT_OFF;
  const __bf16* Qb  = ws + QB_OFF;
  const __bf16* Kb  = ws + KB_OFF;
  const __bf16* Vt  = ws + VT_OFF;
  __shared__ __bf16 kv[2][4096];       // [buf][K 64x32 | V 32x64]
  __shared__ __bf16 pbuf[4][16 * 72];  // per-wave P transpose bounce
  __shared__ __bf16 abuf[4][16 * 40];  // per-wave attn bounce
  int tid = threadIdx.x;
  int w = tid >> 6, lane = tid & 63, c = lane & 15, g = lane >> 4;
  int batch = blockIdx.x >> 6, qb = blockIdx.x & 63;
  int qrow0 = batch * 4096 + qb * 64 + w * 16;
  const __bf16* Kbb = Kb + (size_t)batch * 4096 * 32;
  const __bf16* Vtb = Vt + (size_t)batch * 32 * 4096;

  const f32x4 zero = {0.f, 0.f, 0.f, 0.f};
  // Q as B-operand: lane holds Q[q = c][dims 8g..8g+7] (scale*log2e folded)
  bf16x8 qfrag = *(const bf16x8*)(Qb + (size_t)(qrow0 + c) * 32 + g * 8);
  f32x4 acc0 = zero, acc1 = zero;   // acc^T[rv][q=c]: acc0 rv=4g+r, acc1 rv=16+4g+r
  float m = -1e30f, lsum = 0.f;

  stage_kv(kv[0], Kbb, Vtb, 0, w, lane);

  for (int kt = 0; kt < 64; ++kt) {
    __syncthreads();   // drains own vmcnt(0): stage(kt) landed; waves aligned
    if (kt + 1 < 64) stage_kv(kv[(kt + 1) & 1], Kbb, Vtb, kt + 1, w, lane);
    const __bf16* kvb = kv[kt & 1];

    bf16x8 ak[4], av[4];
#pragma unroll
    for (int i = 0; i < 4; ++i)
      ak[i] = *(const bf16x8*)(kvb + (i * 16 + c) * 32 + g * 8);
#pragma unroll
    for (int t2 = 0; t2 < 2; ++t2)
#pragma unroll
      for (int ks = 0; ks < 2; ++ks)
        av[t2 * 2 + ks] = *(const bf16x8*)(kvb + 2048 + (t2 * 16 + c) * 64 +
                                           (((ks << 2) | g) ^ (c & 7)) * 8);

    // S^T[key=16i+4g+r][q=c], scores already in log2 domain
    f32x4 sr[4];
#pragma unroll
    for (int i = 0; i < 4; ++i) sr[i] = MFMA16(ak[i], qfrag, zero);

    float mx = sr[0][0];
#pragma unroll
    for (int i = 0; i < 4; ++i)
#pragma unroll
      for (int r = 0; r < 4; ++r) mx = fmaxf(mx, sr[i][r]);
    mx = fmaxf(mx, __shfl_xor(mx, 16, 64));
    mx = fmaxf(mx, __shfl_xor(mx, 32, 64));
    float mn = fmaxf(m, mx);
    float corr = exp2f(m - mn);
    m = mn;
    float ps = 0.f;
    float p[4][4];
#pragma unroll
    for (int i = 0; i < 4; ++i)
#pragma unroll
      for (int r = 0; r < 4; ++r) {
        p[i][r] = exp2f(sr[i][r] - mn);
        ps += p[i][r];
      }
    ps += __shfl_xor(ps, 16, 64);
    ps += __shfl_xor(ps, 32, 64);
    lsum = lsum * corr + ps;
#pragma unroll
    for (int r = 0; r < 4; ++r) { acc0[r] *= corr; acc1[r] *= corr; }

    // P^T -> per-wave LDS as [q][64 keys] (write transposed, read as B-frags)
    __bf16* pw = pbuf[w] + c * 72;
#pragma unroll
    for (int i = 0; i < 4; ++i)
#pragma unroll
      for (int r = 0; r < 4; ++r)
        pw[16 * i + 4 * g + r] = (__bf16)p[i][r];
    asm volatile("s_waitcnt lgkmcnt(0)" ::: "memory");
    __builtin_amdgcn_sched_barrier(0);
    bf16x8 pf0 = *(const bf16x8*)(pbuf[w] + c * 72 + g * 8);
    bf16x8 pf1 = *(const bf16x8*)(pbuf[w] + c * 72 + 32 + g * 8);

    acc0 = MFMA16(av[0], pf0, acc0);
    acc0 = MFMA16(av[1], pf1, acc0);
    acc1 = MFMA16(av[2], pf0, acc1);
    acc1 = MFMA16(av[3], pf1, acc1);
  }

  // normalize, bounce attn to [q][32 rv], fused @ Wo + bo
  float inv = 1.0f / lsum;
#pragma unroll
  for (int r = 0; r < 4; ++r) { acc0[r] *= inv; acc1[r] *= inv; }
  __bf16* aw = abuf[w] + c * 40;
#pragma unroll
  for (int r = 0; r < 4; ++r) {
    aw[4 * g + r] = (__bf16)acc0[r];
    aw[16 + 4 * g + r] = (__bf16)acc1[r];
  }
  asm volatile("s_waitcnt lgkmcnt(0)" ::: "memory");
  __builtin_amdgcn_sched_barrier(0);
  bf16x8 aa = *(const bf16x8*)(abuf[w] + c * 40 + g * 8);
#pragma unroll 4
  for (int nf = 0; nf < 64; ++nf) {
    bf16x8 bw = *(const bf16x8*)(Wot + (nf * 16 + c) * 32 + g * 8);
    f32x4 o = MFMA16(aa, bw, zero);
    float bias = bo[nf * 16 + c];
    float* op = out + (size_t)(qrow0 + 4 * g) * 1024 + nf * 16 + c;
#pragma unroll
    for (int r = 0; r < 4; ++r) op[(size_t)r * 1024] = o[r] + bias;
  }
}

extern "C" void kernel_launch(void* const* d_in, const int* in_sizes, int n_in,
                              void* d_out, int out_size, void* d_ws, size_t ws_size,
                              hipStream_t stream) {
  const float* x  = (const float*)d_in[0];
  const float* Wq = (const float*)d_in[1];
  const float* bq = (const float*)d_in[2];
  const float* Wk = (const float*)d_in[3];
  const float* bk = (const float*)d_in[4];
  const float* Wv = (const float*)d_in[5];
  const float* bv = (const float*)d_in[6];
  const float* Wo = (const float*)d_in[7];
  const float* bo = (const float*)d_in[8];
  float* out = (float*)d_out;
  __bf16* ws = (__bf16*)d_ws;
  prep_kernel<<<dim3(512), dim3(256), 0, stream>>>(Wq, Wk, Wv, Wo, ws);
  proj_kernel<<<dim3(1024), dim3(64), 0, stream>>>(x, bq, bk, bv, ws);
  flash_kernel<<<dim3(256), dim3(256), 0, stream>>>(bo, out, ws);
}

// Round 8
// 193.571 us; speedup vs baseline: 1.2284x; 1.1281x over previous
//
#include <hip/hip_runtime.h>

typedef __bf16 bf16x8 __attribute__((ext_vector_type(8)));
typedef float f32x4 __attribute__((ext_vector_type(4)));
typedef unsigned int u32;

#define MFMA16(a, b, c) __builtin_amdgcn_mfma_f32_16x16x32_bf16((a), (b), (c), 0, 0, 0)

// ws element offsets (__bf16 units)
#define WT_OFF   0        // Wt  [96][1024]   (W^T for Q|K|V, Wq pre-scaled by scale*log2e)
#define WOT_OFF  98304    // Wot [1024][32]   (Wo^T)
#define QB_OFF   131072   // Qb  [16384][32]
#define KB_OFF   655360   // Kb  [16384][32]
#define VT_OFF   1179648  // Vt  [4][32][4096]

#define SCALE_QL (0.17677669529663689f * 1.4426950408889634f)  // rank^-0.5 * log2(e)

__device__ __forceinline__ void load_lds16(void* lds, const void* gsrc) {
  __builtin_amdgcn_global_load_lds(
      (const __attribute__((address_space(1))) unsigned int*)gsrc,
      (__attribute__((address_space(3))) unsigned int*)lds, 16, 0, 0);
}

__global__ __launch_bounds__(256) void prep_kernel(
    const float* __restrict__ Wq, const float* __restrict__ Wk,
    const float* __restrict__ Wv, const float* __restrict__ Wo,
    __bf16* __restrict__ ws) {
  int idx = blockIdx.x * 256 + threadIdx.x;
  if (idx < 98304) {            // Wt[n][d] = W[d][n], n in [0,96)
    int n = idx >> 10, d = idx & 1023;
    float v;
    if (n < 32)      v = Wq[d * 32 + n] * SCALE_QL;
    else if (n < 64) v = Wk[d * 32 + (n - 32)];
    else             v = Wv[d * 32 + (n - 64)];
    ws[WT_OFF + idx] = (__bf16)v;
  } else if (idx < 131072) {    // Wot[d][r] = Wo[r][d]
    int j = idx - 98304;
    int d = j >> 5, r = j & 31;
    ws[WOT_OFF + j] = (__bf16)Wo[r * 1024 + d];
  }
}

// ---------------- QKV projection (unchanged this round) -------------------
__device__ __forceinline__ void stage_x(float* lbase, const float* x, int r0,
                                        int tt, int lane) {
#pragma unroll
  for (int j = 0; j < 4; ++j) {
    int row = j * 4 + (lane >> 4);
    int ch = lane & 15;
    int gc = (ch & 8) | ((ch & 7) ^ (row & 7));   // XOR-swizzle 16B chunks
    const float* src = x + (size_t)(r0 + row) * 1024 + tt * 64 + gc * 4;
    load_lds16(lbase + j * 256, src);
  }
}

__device__ __forceinline__ void load_w(bf16x8* w, const __bf16* Wt, int t,
                                       int c, int g) {
#pragma unroll
  for (int ks = 0; ks < 2; ++ks)
#pragma unroll
    for (int nf = 0; nf < 6; ++nf)
      w[ks * 6 + nf] =
          *(const bf16x8*)(Wt + (size_t)(nf * 16 + c) * 1024 + t * 64 + ks * 32 + g * 8);
}

__global__ __launch_bounds__(64) void proj_kernel(
    const float* __restrict__ x, const float* __restrict__ bq,
    const float* __restrict__ bk, const float* __restrict__ bv,
    __bf16* __restrict__ ws) {
  __shared__ float xlds[4 * 16 * 64];  // 4 bufs x (16 rows x 64 f32), swizzled
  const __bf16* Wt = ws + WT_OFF;
  __bf16* Qb = ws + QB_OFF;
  __bf16* Kb = ws + KB_OFF;
  __bf16* Vt = ws + VT_OFF;
  int lane = threadIdx.x;
  int c = lane & 15, g = lane >> 4;
  int r0 = blockIdx.x * 16;

#pragma unroll
  for (int tt = 0; tt < 4; ++tt) stage_x(xlds + tt * 1024, x, r0, tt, lane);
  __builtin_amdgcn_sched_barrier(0);
  bf16x8 wcur[12], wnext[12];
  load_w(wcur, Wt, 0, c, g);
  __builtin_amdgcn_sched_barrier(0);

  f32x4 acc[6];
#pragma unroll
  for (int i = 0; i < 6; ++i) acc[i] = (f32x4){0.f, 0.f, 0.f, 0.f};

  for (int t = 0; t < 16; ++t) {
    __builtin_amdgcn_sched_barrier(0);
    if (t + 1 < 16) load_w(wnext, Wt, t + 1, c, g);
    __builtin_amdgcn_sched_barrier(0);
    if (t == 0)      asm volatile("s_waitcnt vmcnt(12)" ::: "memory");
    else if (t < 12) asm volatile("s_waitcnt vmcnt(16)" ::: "memory");
    else             asm volatile("s_waitcnt vmcnt(0)" ::: "memory");
    __builtin_amdgcn_sched_barrier(0);

    const float* xt = xlds + (t & 3) * 1024;
#pragma unroll
    for (int ks = 0; ks < 2; ++ks) {
      int cha = (ks << 3) | ((2 * g) ^ (c & 7));
      int chb = (ks << 3) | (((2 * g) | 1) ^ (c & 7));
      f32x4 xa = *(const f32x4*)(xt + c * 64 + cha * 4);
      f32x4 xb = *(const f32x4*)(xt + c * 64 + chb * 4);
      bf16x8 a;
      a[0] = (__bf16)xa[0]; a[1] = (__bf16)xa[1];
      a[2] = (__bf16)xa[2]; a[3] = (__bf16)xa[3];
      a[4] = (__bf16)xb[0]; a[5] = (__bf16)xb[1];
      a[6] = (__bf16)xb[2]; a[7] = (__bf16)xb[3];
#pragma unroll
      for (int nf = 0; nf < 6; ++nf)
        acc[nf] = MFMA16(a, wcur[ks * 6 + nf], acc[nf]);
    }
    __builtin_amdgcn_sched_barrier(0);
    if (t + 4 < 16) stage_x(xlds + (t & 3) * 1024, x, r0, t + 4, lane);
#pragma unroll
    for (int i = 0; i < 12; ++i) wcur[i] = wnext[i];
  }

#pragma unroll
  for (int nf = 0; nf < 6; ++nf) {
    int n = nf * 16 + c;
    float bias = (n < 32) ? bq[n] * SCALE_QL : (n < 64 ? bk[n - 32] : bv[n - 64]);
#pragma unroll
    for (int r = 0; r < 4; ++r) {
      int row = r0 + 4 * g + r;
      float v = acc[nf][r] + bias;
      if (n < 32)      Qb[row * 32 + n] = (__bf16)v;
      else if (n < 64) Kb[row * 32 + (n - 32)] = (__bf16)v;
      else {
        int batch = row >> 12, s = row & 4095;
        Vt[((size_t)(batch * 32 + (n - 64))) * 4096 + s] = (__bf16)v;
      }
    }
  }
}

// ---------------- flash attention v3: in-block K-split ---------------------
// 1024 blocks x 4 waves. Block = 16 q rows; wave w owns keys [w*1024,(w+1)*1024).
// No barriers in the main loop (waves independent -> 16 waves/CU, 4/SIMD).
// Swapped QK^T (mfma(K,Q) -> S^T, lane-local softmax), P packed via
// v_cvt_pk_bf16_f32 + ds_write_b64 (stride-72 rows: 16B-aligned b128 reads).
// Epilogue: flash-merge of 4 partials in LDS, then fused @Wo + bo.
__global__ __launch_bounds__(256, 4) void flash_kernel(
    const float* __restrict__ bo, float* __restrict__ out,
    const __bf16* __restrict__ ws) {
  const __bf16* Wot = ws + WOT_OFF;
  const __bf16* Qb  = ws + QB_OFF;
  const __bf16* Kb  = ws + KB_OFF;
  const __bf16* Vt  = ws + VT_OFF;
  __shared__ __bf16 pbuf[4][16 * 72];   // per-wave P^T bounce, row stride 72
  __shared__ float  pacc[4][32 * 16];   // partial attn^T [w][rv][q]
  __shared__ float2 mlbuf[4][16];       // (m, lsum) [w][q]
  __shared__ __bf16 abuf[16 * 40];      // merged attn [q][rv], row stride 40
  int tid = threadIdx.x;
  int w = tid >> 6, lane = tid & 63, c = lane & 15, g = lane >> 4;
  int batch = blockIdx.x >> 8, qt = blockIdx.x & 255;
  int qrow0 = batch * 4096 + qt * 16;
  const __bf16* Kbb = Kb + (size_t)batch * 4096 * 32;
  const __bf16* Vtb = Vt + (size_t)batch * 32 * 4096;
  int kbase = w * 1024;

  const f32x4 zero = {0.f, 0.f, 0.f, 0.f};
  // Q as B-operand: lane holds Q[q=c][dims 8g..8g+7] (scale*log2e folded)
  bf16x8 qfrag = *(const bf16x8*)(Qb + (size_t)(qrow0 + c) * 32 + g * 8);
  f32x4 acc0 = zero, acc1 = zero;  // attn^T partial: acc0 rv=4g+r, acc1 rv=16+4g+r
  float m = -1e30f, lsum = 0.f;

  for (int kt = 0; kt < 16; ++kt) {
    int k0 = kbase + kt * 64;
    bf16x8 ak[4], av[4];
#pragma unroll
    for (int i = 0; i < 4; ++i)
      ak[i] = *(const bf16x8*)(Kbb + (size_t)(k0 + i * 16 + c) * 32 + g * 8);
#pragma unroll
    for (int t2 = 0; t2 < 2; ++t2)
#pragma unroll
      for (int ks = 0; ks < 2; ++ks)
        av[t2 * 2 + ks] =
            *(const bf16x8*)(Vtb + (size_t)(t2 * 16 + c) * 4096 + k0 + ks * 32 + g * 8);

    // S^T[key=16i+4g+r][q=c], log2 domain
    f32x4 sr[4];
#pragma unroll
    for (int i = 0; i < 4; ++i) sr[i] = MFMA16(ak[i], qfrag, zero);

    float mx = sr[0][0];
#pragma unroll
    for (int i = 0; i < 4; ++i)
#pragma unroll
      for (int r = 0; r < 4; ++r) mx = fmaxf(mx, sr[i][r]);
    mx = fmaxf(mx, __shfl_xor(mx, 16, 64));
    mx = fmaxf(mx, __shfl_xor(mx, 32, 64));
    float mn = fmaxf(m, mx);
    float corr = exp2f(m - mn);
    m = mn;

    // exp2, pack to bf16 pairs, sum; write P^T row (keys 4g..4g+3 per i) as b64
    float ps = 0.f;
    __bf16* pw = pbuf[w] + c * 72;
#pragma unroll
    for (int i = 0; i < 4; ++i) {
      float p0 = exp2f(sr[i][0] - mn), p1 = exp2f(sr[i][1] - mn);
      float p2 = exp2f(sr[i][2] - mn), p3 = exp2f(sr[i][3] - mn);
      ps += (p0 + p1) + (p2 + p3);
      u32 lo, hi;
      asm("v_cvt_pk_bf16_f32 %0, %1, %2" : "=v"(lo) : "v"(p0), "v"(p1));
      asm("v_cvt_pk_bf16_f32 %0, %1, %2" : "=v"(hi) : "v"(p2), "v"(p3));
      uint2 pr; pr.x = lo; pr.y = hi;
      *(uint2*)(pw + 16 * i + 4 * g) = pr;
    }
    ps += __shfl_xor(ps, 16, 64);
    ps += __shfl_xor(ps, 32, 64);
    lsum = lsum * corr + ps;
#pragma unroll
    for (int r = 0; r < 4; ++r) { acc0[r] *= corr; acc1[r] *= corr; }

    asm volatile("s_waitcnt lgkmcnt(0)" ::: "memory");
    __builtin_amdgcn_sched_barrier(0);
    bf16x8 pf0 = *(const bf16x8*)(pbuf[w] + c * 72 + g * 8);
    bf16x8 pf1 = *(const bf16x8*)(pbuf[w] + c * 72 + 32 + g * 8);

    acc0 = MFMA16(av[0], pf0, acc0);
    acc0 = MFMA16(av[1], pf1, acc0);
    acc1 = MFMA16(av[2], pf0, acc1);
    acc1 = MFMA16(av[3], pf1, acc1);
  }

  // ---- merge 4 K-split partials (standard online-softmax combine) ----
#pragma unroll
  for (int r = 0; r < 4; ++r) {
    pacc[w][(4 * g + r) * 16 + c] = acc0[r];
    pacc[w][(16 + 4 * g + r) * 16 + c] = acc1[r];
  }
  if (g == 0) { float2 ml; ml.x = m; ml.y = lsum; mlbuf[w][c] = ml; }
  __syncthreads();

#pragma unroll
  for (int p2 = 0; p2 < 2; ++p2) {
    int idx = tid + p2 * 256;          // 0..511 = 16 q x 32 rv
    int q = idx & 15, rv = idx >> 4;
    float M = mlbuf[0][q].x;
#pragma unroll
    for (int w2 = 1; w2 < 4; ++w2) M = fmaxf(M, mlbuf[w2][q].x);
    float L = 0.f, val = 0.f;
#pragma unroll
    for (int w2 = 0; w2 < 4; ++w2) {
      float2 ml = mlbuf[w2][q];
      float sc = exp2f(ml.x - M);
      L += ml.y * sc;
      val += pacc[w2][rv * 16 + q] * sc;
    }
    abuf[q * 40 + rv] = (__bf16)(val / L);
  }
  __syncthreads();

  // ---- fused out-proj: wave w covers nf = 16w .. 16w+15 ----
  bf16x8 aa = *(const bf16x8*)(abuf + c * 40 + g * 8);
#pragma unroll 4
  for (int j = 0; j < 16; ++j) {
    int nf = w * 16 + j;
    bf16x8 bw = *(const bf16x8*)(Wot + (size_t)(nf * 16 + c) * 32 + g * 8);
    f32x4 o = MFMA16(aa, bw, zero);
    float bias = bo[nf * 16 + c];
    float* op = out + (size_t)(qrow0 + 4 * g) * 1024 + nf * 16 + c;
#pragma unroll
    for (int r = 0; r < 4; ++r) op[(size_t)r * 1024] = o[r] + bias;
  }
}

extern "C" void kernel_launch(void* const* d_in, const int* in_sizes, int n_in,
                              void* d_out, int out_size, void* d_ws, size_t ws_size,
                              hipStream_t stream) {
  const float* x  = (const float*)d_in[0];
  const float* Wq = (const float*)d_in[1];
  const float* bq = (const float*)d_in[2];
  const float* Wk = (const float*)d_in[3];
  const float* bk = (const float*)d_in[4];
  const float* Wv = (const float*)d_in[5];
  const float* bv = (const float*)d_in[6];
  const float* Wo = (const float*)d_in[7];
  const float* bo = (const float*)d_in[8];
  float* out = (float*)d_out;
  __bf16* ws = (__bf16*)d_ws;
  prep_kernel<<<dim3(512), dim3(256), 0, stream>>>(Wq, Wk, Wv, Wo, ws);
  proj_kernel<<<dim3(1024), dim3(64), 0, stream>>>(x, bq, bk, bv, ws);
  flash_kernel<<<dim3(1024), dim3(256), 0, stream>>>(bo, out, ws);
}